// Round 1
// baseline (486.509 us; speedup 1.0000x reference)
//
#include <hip/hip_runtime.h>
#include <math.h>

// Problem constants (match reference)
#define BB 32
#define HQ 32
#define HKV 8
#define DD 128
#define GG 4             // HQ / HKV
#define PAGE_SZ 16
#define PAGES_PER_SEQ 128
#define MAX_LEN 2048
#define CHUNK 64         // tokens per split-K chunk (4 pages)
#define NCHUNK 32        // MAX_LEN / CHUNK
#define SCALING 0.08838834764831845f
#define CAP 50.0f
// per-(b,chunk) workspace: 32 m + 32 l + 32*128 O floats
#define WS_STRIDE 4160   // needs BB*NCHUNK*4160*4 = 17.04 MB of d_ws

// Sum over each 8-lane group via DPP row_shr (VALU pipe, no LDS traffic).
// After shr1+shr2+shr4, lanes 7 and 15 (mod 16) hold their group's sum.
__device__ __forceinline__ float dpp8_sum(float x) {
    int t;
    t = __builtin_amdgcn_update_dpp(0, __float_as_int(x), 0x111, 0xF, 0xF, true);
    x += __int_as_float(t);
    t = __builtin_amdgcn_update_dpp(0, __float_as_int(x), 0x112, 0xF, 0xF, true);
    x += __int_as_float(t);
    t = __builtin_amdgcn_update_dpp(0, __float_as_int(x), 0x114, 0xF, 0xF, true);
    x += __int_as_float(t);
    return x;
}

// One block per (b, chunk) covering ALL 8 KV heads -> fully contiguous
// 64 KB K-slab and 64 KB V-slab streams (DRAM row locality).
// Phase 1: one token per wave-iter; 64 lanes = 8 heads x 8 lanes; wave reads
//          the token's full 4 KB slot. DPP8 reduce within each 8-lane group.
// Phase 2: half-wave <-> head; token per iter, d-per-lane. Accumulator is
//          complete per half-wave (no cross-wave reduce). V pipelined 4-deep.
__global__ __launch_bounds__(256, 4) void attn_partial(
    const float* __restrict__ q,        // [B, HQ*D]
    const float* __restrict__ knew,     // [B, HKV*D]
    const float* __restrict__ vnew,     // [B, HKV*D]
    const float* __restrict__ k_cache,  // [NUM_PAGES, PAGE_SZ, HKV, D]
    const float* __restrict__ v_cache,
    const int* __restrict__ page_table, // [B, PAGES_PER_SEQ]
    const int* __restrict__ seq_lens,   // [B]
    float* __restrict__ ws)
{
    const int idx = blockIdx.x;
    const int c = idx % NCHUNK;
    const int b = idx / NCHUNK;
    const int tid = threadIdx.x;

    const int L  = seq_lens[b];
    const int t0 = c * CHUNK;
    float* wsb = ws + (size_t)idx * WS_STRIDE;

    if (t0 >= L) {
        if (tid < 32) { wsb[tid] = -INFINITY; wsb[32 + tid] = 0.0f; }
        return;
    }
    const int t1 = min(t0 + CHUNK, L);
    const int NT = t1 - t0;

    __shared__ float s_sc[HKV * GG][CHUNK + 1];   // stride 65: conflict-free writes
    __shared__ int   s_pages[CHUNK / PAGE_SZ];
    __shared__ float s_m[32], s_l[32];

    if (tid < CHUNK / PAGE_SZ)
        s_pages[tid] = page_table[b * PAGES_PER_SEQ + (t0 >> 4) + tid];
    __syncthreads();

    const float* knew_b = knew + (size_t)b * (HKV * DD);
    const float* vnew_b = vnew + (size_t)b * (HKV * DD);

    // ---- phase 1: QK^T, one token per wave-iter, 8h x 8lanes ----
    {
        const int wv = tid >> 6;    // wave 0..3 -> token stride 4
        const int ln = tid & 63;
        const int hh = ln >> 3;     // kv head 0..7
        const int lg = ln & 7;      // owns d in {lg*4 + p*32}

        float4 qf[GG][4];
        const float* qb = q + (size_t)b * (HQ * DD) + (hh * GG) * DD + lg * 4;
        #pragma unroll
        for (int g = 0; g < GG; g++)
            #pragma unroll
            for (int p = 0; p < 4; p++)
                qf[g][p] = *(const float4*)(qb + g * DD + p * 32);

        const int niter = (NT + 3) >> 2;

#define LOAD_K(I, KV, WT) do {                                                \
        int tt_ = (I) * 4 + wv;                                               \
        bool vld_ = tt_ < NT;                                                 \
        int tc_ = vld_ ? tt_ : NT - 1;                                        \
        int t_ = t0 + tc_;                                                    \
        const float* slab_;                                                   \
        if (t_ == L - 1) slab_ = knew_b;  /* wave-uniform branch */           \
        else {                                                                \
            int pg_ = s_pages[tc_ >> 4];                                      \
            slab_ = k_cache + ((size_t)pg_ * PAGE_SZ + (t_ & (PAGE_SZ - 1)))  \
                              * (HKV * DD);                                   \
        }                                                                     \
        const float* row_ = slab_ + hh * DD + lg * 4;                         \
        KV[0] = *(const float4*)(row_);                                       \
        KV[1] = *(const float4*)(row_ + 32);                                  \
        KV[2] = *(const float4*)(row_ + 64);                                  \
        KV[3] = *(const float4*)(row_ + 96);                                  \
        WT = vld_ ? tt_ : -1;                                                 \
    } while (0)

        float4 kva[4]; int wta;
        LOAD_K(0, kva, wta);
        for (int i = 0; i < niter; i++) {
            float4 kvb[4]; int wtb = -1;
            if (i + 1 < niter) LOAD_K(i + 1, kvb, wtb);

            float dots[GG];
            #pragma unroll
            for (int g = 0; g < GG; g++) {
                float s = 0.0f;
                #pragma unroll
                for (int p = 0; p < 4; p++)
                    s += kva[p].x * qf[g][p].x + kva[p].y * qf[g][p].y
                       + kva[p].z * qf[g][p].z + kva[p].w * qf[g][p].w;
                dots[g] = dpp8_sum(s);
            }
            if (lg == 7 && wta >= 0) {
                #pragma unroll
                for (int g = 0; g < GG; g++) s_sc[hh * GG + g][wta] = dots[g];
            }
            #pragma unroll
            for (int p = 0; p < 4; p++) kva[p] = kvb[p];
            wta = wtb;
        }
#undef LOAD_K
    }
    __syncthreads();

    // ---- phase 1.5: scale + cap + max + exp + sum; 8 lanes per (h,g) row ----
    {
        const int r  = tid >> 3;    // (h*4+g) 0..31
        const int lg = tid & 7;
        float* row = s_sc[r];
        const int tb = lg * 8;      // contiguous 8 tokens -> 2-way banks (free)
        float mx = -INFINITY;
        #pragma unroll
        for (int j = 0; j < 8; j++) {
            int t = tb + j;
            if (t < NT) {
                float s = row[t];
                s = CAP * tanhf(s * (SCALING * (1.0f / CAP)));
                row[t] = s;
                mx = fmaxf(mx, s);
            }
        }
        mx = fmaxf(mx, __shfl_xor(mx, 1, 8));
        mx = fmaxf(mx, __shfl_xor(mx, 2, 8));
        mx = fmaxf(mx, __shfl_xor(mx, 4, 8));
        float sum = 0.0f;
        #pragma unroll
        for (int j = 0; j < 8; j++) {
            int t = tb + j;
            if (t < NT) {
                float e = __expf(row[t] - mx);
                row[t] = e;
                sum += e;
            }
        }
        sum += __shfl_xor(sum, 1, 8);
        sum += __shfl_xor(sum, 2, 8);
        sum += __shfl_xor(sum, 4, 8);
        if (lg == 0) { s_m[r] = mx; s_l[r] = sum; }
    }
    __syncthreads();

    // ---- phase 2: O += p * V; half-wave = head, token per iter, 4-deep ----
    {
        const int hw = tid >> 5;    // kv head 0..7
        const int l2 = tid & 31;    // d quarter: d = l2*4

        float4 acc[GG];
        #pragma unroll
        for (int g = 0; g < GG; g++) acc[g] = make_float4(0.f, 0.f, 0.f, 0.f);

#define LOAD_V(TT, DST) do {                                                  \
        int tc_ = (TT) < NT ? (TT) : NT - 1;  /* clamp: safe re-read */       \
        int t_ = t0 + tc_;                                                    \
        const float* slab_;                                                   \
        if (t_ == L - 1) slab_ = vnew_b;                                      \
        else {                                                                \
            int pg_ = s_pages[tc_ >> 4];                                      \
            slab_ = v_cache + ((size_t)pg_ * PAGE_SZ + (t_ & (PAGE_SZ - 1)))  \
                              * (HKV * DD);                                   \
        }                                                                     \
        DST = *(const float4*)(slab_ + hw * DD + l2 * 4);                     \
    } while (0)

#define USE_V(TT, VV) do {                                                    \
        int tt_ = (TT);                                                       \
        if (tt_ < NT) {                                                       \
            float p0 = s_sc[hw * GG + 0][tt_];                                \
            float p1 = s_sc[hw * GG + 1][tt_];                                \
            float p2 = s_sc[hw * GG + 2][tt_];                                \
            float p3 = s_sc[hw * GG + 3][tt_];                                \
            acc[0].x += p0 * VV.x; acc[0].y += p0 * VV.y;                     \
            acc[0].z += p0 * VV.z; acc[0].w += p0 * VV.w;                     \
            acc[1].x += p1 * VV.x; acc[1].y += p1 * VV.y;                     \
            acc[1].z += p1 * VV.z; acc[1].w += p1 * VV.w;                     \
            acc[2].x += p2 * VV.x; acc[2].y += p2 * VV.y;                     \
            acc[2].z += p2 * VV.z; acc[2].w += p2 * VV.w;                     \
            acc[3].x += p3 * VV.x; acc[3].y += p3 * VV.y;                     \
            acc[3].z += p3 * VV.z; acc[3].w += p3 * VV.w;                     \
        }                                                                     \
    } while (0)

        float4 v0, v1, v2, v3;
        LOAD_V(0, v0); LOAD_V(1, v1); LOAD_V(2, v2); LOAD_V(3, v3);
        for (int base = 0; base < NT; base += 4) {
            float4 n0, n1, n2, n3;
            // always prefetch (clamped) -> no uninit regs, no extra branch
            LOAD_V(base + 4, n0); LOAD_V(base + 5, n1);
            LOAD_V(base + 6, n2); LOAD_V(base + 7, n3);
            USE_V(base + 0, v0);
            USE_V(base + 1, v1);
            USE_V(base + 2, v2);
            USE_V(base + 3, v3);
            v0 = n0; v1 = n1; v2 = n2; v3 = n3;
        }
#undef USE_V
#undef LOAD_V

        // O write: complete per half-wave, coalesced float4 stores
        #pragma unroll
        for (int g = 0; g < GG; g++)
            *(float4*)&wsb[64 + (hw * GG + g) * DD + l2 * 4] = acc[g];
        if (tid < 32) { wsb[tid] = s_m[tid]; wsb[32 + tid] = s_l[tid]; }
    }
}

// One block per (b, kv_head); 512 threads = one (g, d) element each.
__global__ __launch_bounds__(512) void attn_combine(
    const float* __restrict__ ws, float* __restrict__ out)
{
    const int bh = blockIdx.x;
    const int h  = bh % HKV;
    const int b  = bh / HKV;
    const int tid = threadIdx.x;   // 0..511
    const int g = tid >> 7;        // 0..3
    const int d = tid & 127;
    const int r = h * GG + g;

    float mv[NCHUNK], lv[NCHUNK];
    float M = -INFINITY;
    #pragma unroll
    for (int cc = 0; cc < NCHUNK; cc++) {
        const float* wsb = ws + (size_t)(b * NCHUNK + cc) * WS_STRIDE;
        mv[cc] = wsb[r];
        lv[cc] = wsb[32 + r];
        if (lv[cc] > 0.0f) M = fmaxf(M, mv[cc]);
    }
    float lsum = 0.0f, osum = 0.0f;
    #pragma unroll
    for (int cc = 0; cc < NCHUNK; cc++) {
        if (lv[cc] > 0.0f) {
            const float* wsb = ws + (size_t)(b * NCHUNK + cc) * WS_STRIDE;
            float a = __expf(mv[cc] - M);
            lsum += lv[cc] * a;
            osum += wsb[64 + r * DD + d] * a;
        }
    }
    out[(size_t)b * (HQ * DD) + r * DD + d] = osum / lsum;
}

extern "C" void kernel_launch(void* const* d_in, const int* in_sizes, int n_in,
                              void* d_out, int out_size, void* d_ws, size_t ws_size,
                              hipStream_t stream) {
    const float* q       = (const float*)d_in[0];
    const float* k       = (const float*)d_in[1];
    const float* v       = (const float*)d_in[2];
    const float* k_cache = (const float*)d_in[3];
    const float* v_cache = (const float*)d_in[4];
    const int* page_table = (const int*)d_in[5];
    const int* seq_lens   = (const int*)d_in[6];
    float* out = (float*)d_out;
    float* ws  = (float*)d_ws;   // needs BB*NCHUNK*WS_STRIDE*4 = 17.04 MB

    attn_partial<<<BB * NCHUNK, 256, 0, stream>>>(
        q, k, v, k_cache, v_cache, page_table, seq_lens, ws);
    attn_combine<<<BB * HKV, 512, 0, stream>>>(ws, out);
}